// Round 12
// baseline (352.873 us; speedup 1.0000x reference)
//
#include <hip/hip_runtime.h>
#include <string.h>

// ---------------------------------------------------------------------------
// HypER pipeline on MI355X. B=8192, D=400, OC=32, FW=9, J=392, R=288,
// FCLEN=12544.
//   M    = W_E @ fc1_w.T            (400x288)      prep_M
//   head = bf16(UE[ht0]) @ bf16(W_E) + bn0 stats   \ gemm_s1_both (merged,
//   k    = bf16(UE[ht1]) @ bf16(M) + fc1_b         /  1024 blocks)
//   conv[b,o,j] -> bf16 convb + per-ch stats       conv_k (bn0 fin fused,
//                                                  8-wide j, 16B nt stores)
//   bn1 -> alpha,beta; fold into fc_w              bn1_fin, prep_fcw (f4 vec)
//   pre  = convb @ Bprep^T  (split-K=4)            fc_gemm_sk:
//          BM=128 BN=80, TRIPLE-buffer LDS 78KB (2 blk/CU), DEPTH-2
//          counted-vmcnt prefetch (own 7|6, never 0 in loop),
//          global_load_lds + XOR swz, bijective XCD swizzle (1280=8x160)
//   reduce partials + bias + bn2 partial stats     reduce_bn2 (512 blocks)
//   bn2 finalize + relu                            bn2_fin, final_k (f4 vec)
// ---------------------------------------------------------------------------

#define BB   8192
#define DD   400
#define RR   288
#define OCC  32
#define FWW  9
#define JJ   392
#define FCLEN 12544
#define KSPL 4
#define KS   (FCLEN / KSPL)   /* 3136 */
#define KSTEPS (KS / 64)      /* 49 */
#define EPSF 1e-5
#define RB2  512              /* reduce_bn2 blocks */

typedef __attribute__((ext_vector_type(8))) short bf16x8;
typedef __attribute__((ext_vector_type(4))) float f32x4;
typedef __attribute__((ext_vector_type(4))) unsigned int u32x4;

__device__ inline unsigned short f2bf(float f) {
    union { float f; unsigned u; } x; x.f = f;
    unsigned r = x.u + 0x7fffu + ((x.u >> 16) & 1u);
    return (unsigned short)(r >> 16);
}

__device__ inline void gload16(const void* g, void* l) {
    __builtin_amdgcn_global_load_lds((const __attribute__((address_space(1))) unsigned int*)g,
                                     (__attribute__((address_space(3))) unsigned int*)l, 16, 0, 0);
}

__device__ inline void nt_store16(void* addr, const unsigned short* v) {
    u32x4 w;
    memcpy(&w, v, 16);
    __builtin_nontemporal_store(w, (u32x4*)addr);
}

__device__ inline float block_reduce_256(float v, float* red) {
    #pragma unroll
    for (int m = 1; m < 64; m <<= 1) v += __shfl_xor(v, m);
    int wv = threadIdx.x >> 6;
    if ((threadIdx.x & 63) == 0) red[wv] = v;
    __syncthreads();
    float r = 0.f;
    if (threadIdx.x == 0) r = red[0] + red[1] + red[2] + red[3];
    return r;
}

// ---------------- prep_M: M[i][r] = sum_d W_E[i][d]*fc1_w[r][d] ------------
__global__ __launch_bounds__(256) void prep_M(const float* __restrict__ WE,
                                              const float* __restrict__ f1w,
                                              float* __restrict__ Mout) {
    __shared__ float sA[16][17];
    __shared__ float sB[16][17];
    int tx = threadIdx.x, ty = threadIdx.y;
    int r0 = blockIdx.x * 16, i0 = blockIdx.y * 16;
    float acc = 0.f;
    for (int d0 = 0; d0 < DD; d0 += 16) {
        sA[ty][tx] = WE[(size_t)(i0 + ty) * DD + d0 + tx];
        sB[ty][tx] = f1w[(size_t)(r0 + ty) * DD + d0 + tx];
        __syncthreads();
        #pragma unroll
        for (int dd = 0; dd < 16; ++dd) acc = fmaf(sA[ty][dd], sB[tx][dd], acc);
        __syncthreads();
    }
    Mout[(size_t)(i0 + ty) * RR + r0 + tx] = acc;
}

// ------------- stage-1 gathered GEMM body (device, shared smem) ------------
#define S1_SMEM (64 * 72 * 2 + 96 * 72 * 2 + 64 * 4 + 8 * 4)

template <int BN>
__device__ __forceinline__ void gemm_s1_body(const float* __restrict__ A,
                                             const int* __restrict__ idx,
                                             const float* __restrict__ Bm,
                                             const float* __restrict__ bias,
                                             float* __restrict__ C, int N,
                                             float* __restrict__ bn0part,
                                             int bm, int bn, char* smem) {
    constexpr int BNF = BN / 16;
    constexpr int BCH = 64 * (BN / 4) / 256;   // B float4-chunks per thread
    typedef unsigned short us;
    us (*Al)[72] = (us (*)[72])smem;
    us (*Bl)[72] = (us (*)[72])(smem + 64 * 72 * 2);
    int* ridx = (int*)(smem + (64 + 96) * 72 * 2);
    float* red = (float*)(ridx + 64);
    int tid = threadIdx.x;
    if (tid < 64) ridx[tid] = idx[bm * 64 + tid];
    int lane = tid & 63, wv = tid >> 6;
    int m16 = lane & 15, kb = lane >> 4;
    f32x4 acc[BNF];
    #pragma unroll
    for (int nb = 0; nb < BNF; ++nb) acc[nb] = (f32x4){0.f, 0.f, 0.f, 0.f};
    __syncthreads();

    float4 av[4];
    float4 bv[BCH];
    auto LOADR = [&](int k0) {
        #pragma unroll
        for (int r = 0; r < 4; ++r) {
            int c = tid + 256 * r;
            int row = c >> 4, kq = c & 15;
            int gk = k0 + kq * 4;
            av[r] = (float4){0.f, 0.f, 0.f, 0.f};
            if (gk < DD) av[r] = *(const float4*)(A + (size_t)ridx[row] * DD + gk);
        }
        #pragma unroll
        for (int r = 0; r < BCH; ++r) {
            int c = tid + 256 * r;
            int kk2 = c / (BN / 4), nq = c % (BN / 4);
            int gk = k0 + kk2;
            bv[r] = (float4){0.f, 0.f, 0.f, 0.f};
            if (gk < DD) bv[r] = *(const float4*)(Bm + (size_t)gk * N + bn * BN + nq * 4);
        }
    };
    auto WRITELDS = [&]() {
        #pragma unroll
        for (int r = 0; r < 4; ++r) {
            int c = tid + 256 * r;
            int row = c >> 4, kq = c & 15;
            ushort4 p;
            p.x = f2bf(av[r].x); p.y = f2bf(av[r].y); p.z = f2bf(av[r].z); p.w = f2bf(av[r].w);
            *(ushort4*)&Al[row][kq * 4] = p;
        }
        #pragma unroll
        for (int r = 0; r < BCH; ++r) {
            int c = tid + 256 * r;
            int kk2 = c / (BN / 4), nq = c % (BN / 4);
            Bl[nq * 4 + 0][kk2] = f2bf(bv[r].x);
            Bl[nq * 4 + 1][kk2] = f2bf(bv[r].y);
            Bl[nq * 4 + 2][kk2] = f2bf(bv[r].z);
            Bl[nq * 4 + 3][kk2] = f2bf(bv[r].w);
        }
    };

    LOADR(0);
    for (int kt = 0; kt < 7; ++kt) {
        WRITELDS();
        __syncthreads();
        if (kt + 1 < 7) LOADR((kt + 1) * 64);   // latency hides under MFMA
        #pragma unroll
        for (int ks = 0; ks < 2; ++ks) {
            bf16x8 a = *(const bf16x8*)&Al[wv * 16 + m16][ks * 32 + kb * 8];
            #pragma unroll
            for (int nb = 0; nb < BNF; ++nb) {
                bf16x8 b = *(const bf16x8*)&Bl[nb * 16 + m16][ks * 32 + kb * 8];
                acc[nb] = __builtin_amdgcn_mfma_f32_16x16x32_bf16(a, b, acc[nb], 0, 0, 0);
            }
        }
        __syncthreads();
    }
    float s1 = 0.f, s2 = 0.f;
    #pragma unroll
    for (int nb = 0; nb < BNF; ++nb)
        #pragma unroll
        for (int rr = 0; rr < 4; ++rr) {
            int gr = bm * 64 + wv * 16 + kb * 4 + rr;
            int gc = bn * BN + nb * 16 + m16;
            float v = acc[nb][rr];
            if (bias) v += bias[gc];
            C[(size_t)gr * N + gc] = v;
            s1 += v; s2 = fmaf(v, v, s2);
        }
    if (bn0part) {
        float t1 = block_reduce_256(s1, red);
        __syncthreads();
        float t2 = block_reduce_256(s2, red);
        if (tid == 0) {
            int pid = bm * 5 + bn;
            bn0part[pid * 2] = t1; bn0part[pid * 2 + 1] = t2;
        }
    }
}

// Merged stage-1: blocks [0,640) do head GEMM (BN=80, bn0 stats); blocks
// [640,1024) do k GEMM (BN=96, +fc1_b). Fills the machine (~4 blocks/CU).
__global__ __launch_bounds__(256) void gemm_s1_both(const float* __restrict__ UE,
                                                    const int* __restrict__ ht,
                                                    const float* __restrict__ WE,
                                                    const float* __restrict__ Mbuf,
                                                    const float* __restrict__ fc1_b,
                                                    float* __restrict__ head,
                                                    float* __restrict__ kbuf,
                                                    float* __restrict__ bn0part) {
    __shared__ char smem[S1_SMEM];
    int bid = blockIdx.x;
    if (bid < 640) {
        gemm_s1_body<80>(UE, ht, WE, nullptr, head, DD, bn0part, bid / 5, bid % 5, smem);
    } else {
        int b2 = bid - 640;
        gemm_s1_body<96>(UE, ht + BB, Mbuf, fc1_b, kbuf, RR, nullptr, b2 / 3, b2 % 3, smem);
    }
}

// ------ per-sample conv: bn0 finalize fused, 8-wide j, 16B nt stores -------
__global__ __launch_bounds__(256) void conv_k(const float* __restrict__ head,
                                              const float* __restrict__ kbuf,
                                              const float* __restrict__ bn0p,
                                              const float* __restrict__ g0,
                                              const float* __restrict__ b0g,
                                              unsigned short* __restrict__ convb,
                                              float* __restrict__ chpartT) {
    __shared__ float xs[DD];
    __shared__ float ks[RR];
    __shared__ float red[8];
    __shared__ float ab[2];
    int b = blockIdx.x, tid = threadIdx.x;
    for (int i = tid; i < DD; i += 256) xs[i] = head[(size_t)b * DD + i];
    for (int i = tid; i < RR; i += 256) ks[i] = kbuf[(size_t)b * RR + i];
    // bn0 finalize (redundant per block, tiny)
    float p1 = 0.f, p2 = 0.f;
    for (int i = tid; i < 640; i += 256) { p1 += bn0p[i * 2]; p2 += bn0p[i * 2 + 1]; }
    float t1 = block_reduce_256(p1, red);
    __syncthreads();
    float t2 = block_reduce_256(p2, red);
    if (tid == 0) {
        double n = (double)BB * DD;
        double mean = (double)t1 / n;
        double var = (double)t2 / n - mean * mean;
        float a0 = (float)((double)g0[0] / sqrt(var + EPSF));
        ab[0] = a0; ab[1] = (float)((double)b0g[0] - mean * a0);
    }
    __syncthreads();
    float a0 = ab[0], b0 = ab[1];
    int lane = tid & 63, wv = tid >> 6;
    unsigned short* orow = convb + (size_t)b * FCLEN;
    float kk[8][FWW];
    #pragma unroll
    for (int oi = 0; oi < 8; ++oi)
        #pragma unroll
        for (int w2 = 0; w2 < FWW; ++w2) kk[oi][w2] = ks[(wv * 8 + oi) * FWW + w2];
    float s1[8], s2[8];
    #pragma unroll
    for (int oi = 0; oi < 8; ++oi) { s1[oi] = 0.f; s2[oi] = 0.f; }
    int j0 = lane * 8;                        // lanes 0..48 active (392/8=49)
    bool act = j0 < JJ;
    float x[16];
    if (act) {
        const float4* x4 = (const float4*)xs;
        float4 v0 = x4[(j0 >> 2) + 0], v1 = x4[(j0 >> 2) + 1];
        float4 v2 = x4[(j0 >> 2) + 2], v3 = x4[(j0 >> 2) + 3];
        float xr[16] = {v0.x, v0.y, v0.z, v0.w, v1.x, v1.y, v1.z, v1.w,
                        v2.x, v2.y, v2.z, v2.w, v3.x, v3.y, v3.z, v3.w};
        #pragma unroll
        for (int q = 0; q < 16; ++q) x[q] = fmaf(xr[q], a0, b0);
    }
    #pragma unroll
    for (int oi = 0; oi < 8; ++oi) {
        if (act) {
            unsigned short p[8];
            #pragma unroll
            for (int q = 0; q < 8; ++q) {
                float a = 0.f;
                #pragma unroll
                for (int w2 = 0; w2 < FWW; ++w2) a = fmaf(x[q + w2], kk[oi][w2], a);
                p[q] = f2bf(a);
                s1[oi] += a; s2[oi] = fmaf(a, a, s2[oi]);
            }
            nt_store16(orow + (wv * 8 + oi) * JJ + j0, p);
        }
    }
    #pragma unroll
    for (int oi = 0; oi < 8; ++oi) {
        float a = s1[oi], c = s2[oi];
        #pragma unroll
        for (int m = 1; m < 64; m <<= 1) { a += __shfl_xor(a, m); c += __shfl_xor(c, m); }
        if (lane == 0) {
            int o = wv * 8 + oi;
            chpartT[(size_t)o * BB + b] = a;
            chpartT[(size_t)(OCC + o) * BB + b] = c;
        }
    }
}

__global__ __launch_bounds__(256) void bn1_fin(const float* __restrict__ chpartT,
                                               const float* __restrict__ g1,
                                               const float* __restrict__ b1,
                                               float* __restrict__ alphabeta) {
    __shared__ float red[8];
    int o = blockIdx.x, tid = threadIdx.x;
    float s1 = 0.f, s2 = 0.f;
    for (int t = tid; t < BB; t += 256) {
        s1 += chpartT[(size_t)o * BB + t];
        s2 += chpartT[(size_t)(OCC + o) * BB + t];
    }
    float t1 = block_reduce_256(s1, red);
    __syncthreads();
    float t2 = block_reduce_256(s2, red);
    if (tid == 0) {
        double n = (double)BB * JJ;
        double mean = (double)t1 / n;
        double var = (double)t2 / n - mean * mean;
        float al = (float)((double)g1[o] / sqrt(var + EPSF));
        float be = (float)((double)b1[o] - mean * al);
        alphabeta[o] = al; alphabeta[OCC + o] = be;
    }
}

// ------- fold bn1 into fc_w: Bprep = bf16(fc_w*alpha); bias2 (f4 vec) ------
__global__ __launch_bounds__(256) void prep_fcw(const float* __restrict__ fc_w,
                                                const float* __restrict__ fc_b,
                                                const float* __restrict__ alphabeta,
                                                unsigned short* __restrict__ Bp,
                                                float* __restrict__ bias2) {
    __shared__ float al[OCC], be[OCC];
    __shared__ float red[8];
    int d = blockIdx.x, tid = threadIdx.x;
    if (tid < OCC) { al[tid] = alphabeta[tid]; be[tid] = alphabeta[OCC + tid]; }
    __syncthreads();
    const float4* row4 = (const float4*)(fc_w + (size_t)d * FCLEN);
    ushort4* orow4 = (ushort4*)(Bp + (size_t)d * FCLEN);
    float bacc = 0.f;
    for (int c = tid; c < FCLEN / 4; c += 256) {     // 3136 float4; 392%4==0
        float4 v = row4[c];
        int o = c / (JJ / 4);                        // c/98
        float a = al[o], bb = be[o];
        ushort4 p;
        p.x = f2bf(v.x * a); p.y = f2bf(v.y * a);
        p.z = f2bf(v.z * a); p.w = f2bf(v.w * a);
        orow4[c] = p;
        bacc = fmaf(v.x + v.y + v.z + v.w, bb, bacc);
    }
    float t = block_reduce_256(bacc, red);
    if (tid == 0) bias2[d] = fc_b[d] + t;
}

// -------- big FC GEMM, split-K=4, BM=128 BN=80, depth-2 counted dbuf -------
// TRIPLE-buffer LDS (3 x 26KB = 78KB -> 2 blocks/CU, 8 waves/CU). At step t:
// issue STAGE(t+2); compute tile t; end-of-step s_waitcnt vmcnt(own 7|6)
// guarantees tile t+1 landed while t+2's loads span TWO steps of MFMA +
// barriers (~500+ cyc) -- the depth-1 attempts (R3/R6/R7/R9) could not
// cover HBM latency. Same XOR swizzle chunks as R8 (refcheck'd, 0 confl);
// bijective XCD swizzle (1280 = 8 x 160).
__global__ __launch_bounds__(256, 2) void fc_gemm_sk(const unsigned short* __restrict__ A,
                                                     const unsigned short* __restrict__ Bp,
                                                     float* __restrict__ P) {
    __shared__ __align__(16) unsigned short Al3[3][128 * 64];   // 3 x 16 KiB
    __shared__ __align__(16) unsigned short Bl3[3][80 * 64];    // 3 x 10 KiB
    int tid = threadIdx.x;
    // bijective XCD swizzle: nwg = 1280 = 8 x 160
    int orig = blockIdx.x;
    int wgid = (orig & 7) * 160 + (orig >> 3);
    int bn = wgid % 5;
    int rest = wgid / 5;            // 0..255
    int bm = rest & 63;
    int bz = rest >> 6;             // 0..3
    int lane = tid & 63, wv = tid >> 6;
    int m16 = lane & 15, kb = lane >> 4;
    int srow = lane >> 3, scol = lane & 7;    // staging: (row-in-chunk, 16B slot)
    int sw = m16 & 7;                          // read-side XOR term (row & 7)
    f32x4 acc[2][5];
    #pragma unroll
    for (int mi = 0; mi < 2; ++mi)
        #pragma unroll
        for (int nb = 0; nb < 5; ++nb) acc[mi][nb] = (f32x4){0.f, 0.f, 0.f, 0.f};

    // per-lane pre-swizzled global sources (chunk = 1KB = 8 rows x 64 cols)
    const unsigned short* Asrc = A + (size_t)(bm * 128 + srow) * FCLEN
                                   + (size_t)bz * KS + ((scol ^ srow) << 3);
    const unsigned short* Bsrc = Bp + (size_t)(bn * 80 + srow) * FCLEN
                                   + (size_t)bz * KS + ((scol ^ srow) << 3);

    // 26 chunks: 16 A + 10 B; wave wv takes chunks wv + 4i
    // -> waves 0,1 issue 7 loads; waves 2,3 issue 6.
    auto STAGE = [&](int t, int buf) {
        const size_t koff = (size_t)t * 64;
        #pragma unroll
        for (int i = 0; i < 7; ++i) {
            int c = wv + i * 4;
            if (c < 16) {
                gload16(Asrc + (size_t)c * 8 * FCLEN + koff, &Al3[buf][c * 512]);
            } else if (c < 26) {
                int cb = c - 16;
                gload16(Bsrc + (size_t)(cb) * 8 * FCLEN + koff, &Bl3[buf][cb * 512]);
            }
        }
    };

    STAGE(0, 0);
    STAGE(1, 1);
    if (wv < 2) asm volatile("s_waitcnt vmcnt(7)" ::: "memory");
    else        asm volatile("s_waitcnt vmcnt(6)" ::: "memory");
    __builtin_amdgcn_s_barrier();
    __builtin_amdgcn_sched_barrier(0);

    for (int t = 0; t < KSTEPS; ++t) {
        int c3 = t % 3;
        bool more2 = (t + 2) < KSTEPS;
        if (more2) {
            int n3 = (t + 2) % 3;
            STAGE(t + 2, n3);
        }
        const unsigned short* Ac = &Al3[c3][0];
        const unsigned short* Bc = &Bl3[c3][0];
        __builtin_amdgcn_s_setprio(1);
        #pragma unroll
        for (int ks2 = 0; ks2 < 2; ++ks2) {
            int ch = (((ks2 * 4 + kb) ^ sw) << 3);
            bf16x8 a[2];
            #pragma unroll
            for (int mi = 0; mi < 2; ++mi)
                a[mi] = *(const bf16x8*)(Ac + (wv * 32 + mi * 16 + m16) * 64 + ch);
            #pragma unroll
            for (int nb = 0; nb < 5; ++nb) {
                bf16x8 b = *(const bf16x8*)(Bc + (nb * 16 + m16) * 64 + ch);
                #pragma unroll
                for (int mi = 0; mi < 2; ++mi)
                    acc[mi][nb] = __builtin_amdgcn_mfma_f32_16x16x32_bf16(a[mi], b, acc[mi][nb], 0, 0, 0);
            }
        }
        __builtin_amdgcn_s_setprio(0);
        asm volatile("s_waitcnt lgkmcnt(0)" ::: "memory");   // reads of buf c3 retired
        if (more2) {
            // tile t+1 landed; tile t+2's loads stay in flight (never 0)
            if (wv < 2) asm volatile("s_waitcnt vmcnt(7)" ::: "memory");
            else        asm volatile("s_waitcnt vmcnt(6)" ::: "memory");
        } else if (t + 1 < KSTEPS) {
            asm volatile("s_waitcnt vmcnt(0)" ::: "memory"); // last prefetched tile
        }
        __builtin_amdgcn_sched_barrier(0);
        __builtin_amdgcn_s_barrier();
        __builtin_amdgcn_sched_barrier(0);
    }

    float* Po = P + (size_t)bz * BB * DD;
    #pragma unroll
    for (int mi = 0; mi < 2; ++mi)
        #pragma unroll
        for (int nb = 0; nb < 5; ++nb)
            #pragma unroll
            for (int rr = 0; rr < 4; ++rr) {
                int gr = bm * 128 + wv * 32 + mi * 16 + kb * 4 + rr;
                int gc = bn * 80 + nb * 16 + m16;
                Po[(size_t)gr * DD + gc] = acc[mi][nb][rr];
            }
}

// ------ reduce split-K partials + bias, emit bn2 per-column partials -------
__global__ __launch_bounds__(256) void reduce_bn2(const float* __restrict__ P,
                                                  const float* __restrict__ bias2,
                                                  float* __restrict__ out,
                                                  float* __restrict__ part) {
    int blk = blockIdx.x, tid = threadIdx.x;   // RB2 blocks x 16 rows
    int r0 = blk * 16;
    const size_t S = (size_t)BB * DD;
    bool hasb = tid < DD - 256;
    float bia = bias2[tid];
    float bib = hasb ? bias2[256 + tid] : 0.f;
    float s1a = 0.f, s2a = 0.f, s1b = 0.f, s2b = 0.f;
    for (int r = 0; r < 16; ++r) {
        size_t base = (size_t)(r0 + r) * DD;
        float v = P[base + tid] + P[S + base + tid] + P[2 * S + base + tid] + P[3 * S + base + tid] + bia;
        out[base + tid] = v;
        s1a += v; s2a = fmaf(v, v, s2a);
        if (hasb) {
            size_t b2i = base + 256 + tid;
            float u = P[b2i] + P[S + b2i] + P[2 * S + b2i] + P[3 * S + b2i] + bib;
            out[b2i] = u;
            s1b += u; s2b = fmaf(u, u, s2b);
        }
    }
    float* p = part + (size_t)blk * (DD * 2);
    p[tid * 2] = s1a; p[tid * 2 + 1] = s2a;
    if (hasb) { p[(256 + tid) * 2] = s1b; p[(256 + tid) * 2 + 1] = s2b; }
}

__global__ __launch_bounds__(128) void bn2_fin(const float* __restrict__ part,
                                               const float* __restrict__ g2,
                                               const float* __restrict__ b2,
                                               float* __restrict__ sc,
                                               float* __restrict__ sh) {
    __shared__ float red[4];
    int col = blockIdx.x, tid = threadIdx.x;
    float s1 = 0.f, s2 = 0.f;
    for (int t = tid; t < RB2; t += 128) {
        s1 += part[(size_t)t * (DD * 2) + col * 2];
        s2 += part[(size_t)t * (DD * 2) + col * 2 + 1];
    }
    #pragma unroll
    for (int m = 1; m < 64; m <<= 1) { s1 += __shfl_xor(s1, m); s2 += __shfl_xor(s2, m); }
    int wv = tid >> 6;
    if ((tid & 63) == 0) { red[wv] = s1; red[2 + wv] = s2; }
    __syncthreads();
    if (tid == 0) {
        double t1 = (double)red[0] + red[1];
        double t2 = (double)red[2] + red[3];
        double mean = t1 / (double)BB;
        double var = t2 / (double)BB - mean * mean;
        float s = (float)((double)g2[col] / sqrt(var + EPSF));
        sc[col] = s;
        sh[col] = (float)((double)b2[col] - mean * s);
    }
}

// ---------------- final scale+shift+relu, float4-vectorized ----------------
__global__ __launch_bounds__(256) void final_k(float* __restrict__ out,
                                               const float* __restrict__ sc,
                                               const float* __restrict__ sh) {
    __shared__ float lsc[DD], lsh[DD];
    int tid = threadIdx.x;
    for (int c = tid; c < DD; c += 256) { lsc[c] = sc[c]; lsh[c] = sh[c]; }
    __syncthreads();
    int r0 = blockIdx.x * 8;                       // 1024 blocks x 8 rows
    float4* out4 = (float4*)(out + (size_t)r0 * DD);
    for (int c = tid; c < 8 * DD / 4; c += 256) {  // 800 float4
        int row = c / (DD / 4), c4 = c % (DD / 4);
        float4 v = out4[(size_t)row * (DD / 4) + c4];
        int cb = c4 * 4;
        v.x = fmaf(v.x, lsc[cb + 0], lsh[cb + 0]); v.x = v.x > 0.f ? v.x : 0.f;
        v.y = fmaf(v.y, lsc[cb + 1], lsh[cb + 1]); v.y = v.y > 0.f ? v.y : 0.f;
        v.z = fmaf(v.z, lsc[cb + 2], lsh[cb + 2]); v.z = v.z > 0.f ? v.z : 0.f;
        v.w = fmaf(v.w, lsc[cb + 3], lsh[cb + 3]); v.w = v.w > 0.f ? v.w : 0.f;
        out4[(size_t)row * (DD / 4) + c4] = v;
    }
}

// ---------------------------------------------------------------------------
extern "C" void kernel_launch(void* const* d_in, const int* in_sizes, int n_in,
                              void* d_out, int out_size, void* d_ws, size_t ws_size,
                              hipStream_t stream) {
    const int* ht      = (const int*)d_in[0];
    const float* UE    = (const float*)d_in[1];
    const float* W_E   = (const float*)d_in[2];
    const float* fc1_w = (const float*)d_in[3];
    const float* fc1_b = (const float*)d_in[4];
    const float* fc_w  = (const float*)d_in[5];
    const float* fc_b  = (const float*)d_in[6];
    const float* bn0_g = (const float*)d_in[7];
    const float* bn0_b = (const float*)d_in[8];
    const float* bn1_g = (const float*)d_in[9];
    const float* bn1_b = (const float*)d_in[10];
    const float* bn2_g = (const float*)d_in[11];
    const float* bn2_b = (const float*)d_in[12];
    float* out = (float*)d_out;

    char* w = (char*)d_ws;
    unsigned short* convb = (unsigned short*)w; w += (size_t)BB * FCLEN * 2;      // 205.5 MB
    unsigned short* Bprep = (unsigned short*)w; w += (size_t)DD * FCLEN * 2;      // 10 MB
    float* chpartT = (float*)w; w += (size_t)2 * OCC * BB * 4;                    // 2.1 MB
    float* bn0p = (float*)w;  w += 640 * 2 * 4;
    float* alphabeta = (float*)w; w += 64 * 4;
    float* bias2 = (float*)w; w += DD * 4;
    float* bn2p = (float*)w;  w += (size_t)RB2 * DD * 2 * 4;
    float* bn2sc = (float*)w; w += DD * 4;
    float* bn2sh = (float*)w; w += DD * 4;
    // split-K partial region (52.4 MB), aliased over head/kbuf/Mbuf (dead by
    // the time fc_gemm_sk runs):
    float* P = (float*)w;     w += (size_t)KSPL * BB * DD * 4;
    float* head = P;                      // 13.1 MB, consumed by conv_k
    float* kbuf = head + (size_t)BB * DD; // 9.4 MB, consumed by conv_k
    float* Mbuf = kbuf + (size_t)BB * RR; // 0.46 MB, consumed by gemm_s1_both
    (void)ws_size; (void)in_sizes; (void)n_in; (void)out_size;

    prep_M<<<dim3(RR / 16, DD / 16), dim3(16, 16), 0, stream>>>(W_E, fc1_w, Mbuf);
    gemm_s1_both<<<1024, 256, 0, stream>>>(UE, ht, W_E, Mbuf, fc1_b, head, kbuf, bn0p);
    conv_k<<<BB, 256, 0, stream>>>(head, kbuf, bn0p, bn0_g, bn0_b, convb, chpartT);
    bn1_fin<<<OCC, 256, 0, stream>>>(chpartT, bn1_g, bn1_b, alphabeta);
    prep_fcw<<<DD, 256, 0, stream>>>(fc_w, fc_b, alphabeta, Bprep, bias2);
    fc_gemm_sk<<<dim3(64 * 5 * KSPL), 256, 0, stream>>>(convb, Bprep, P);
    reduce_bn2<<<RB2, 256, 0, stream>>>(P, bias2, out, bn2p);
    bn2_fin<<<DD, 128, 0, stream>>>(bn2p, bn2_g, bn2_b, bn2sc, bn2sh);
    final_k<<<BB / 8, 256, 0, stream>>>(out, bn2sc, bn2sh);
}

// Round 13
// 294.534 us; speedup vs baseline: 1.1981x; 1.1981x over previous
//
#include <hip/hip_runtime.h>
#include <string.h>

// ---------------------------------------------------------------------------
// HypER pipeline on MI355X. B=8192, D=400, OC=32, FW=9, J=392, R=288,
// FCLEN=12544.  [R11 configuration — best verified: 296.5 us]
//   M    = W_E @ fc1_w.T            (400x288)      prep_M
//   head = bf16(UE[ht0]) @ bf16(W_E) + bn0 stats   \ gemm_s1_both (merged,
//   k    = bf16(UE[ht1]) @ bf16(M) + fc1_b         /  1024 blocks)
//   conv[b,o,j] -> bf16 convb + per-ch stats       conv_k (bn0 fin fused,
//                                                  8-wide j, 16B nt stores)
//   bn1 -> alpha,beta; fold into fc_w              bn1_fin, prep_fcw (f4 vec)
//   pre  = convb @ Bprep^T  (split-K=4)            fc_gemm_sk  [R8 structure:
//          BM=256 BN=80, single-buffer LDS 42KB, global_load_lds + XOR swz,
//          3 blocks/CU, bijective XCD swizzle]
//   reduce partials + bias + bn2 partial stats     reduce_bn2 (512 blocks)
//   bn2 finalize + relu                            bn2_fin, final_k (f4 vec)
// ---------------------------------------------------------------------------

#define BB   8192
#define DD   400
#define RR   288
#define OCC  32
#define FWW  9
#define JJ   392
#define FCLEN 12544
#define KSPL 4
#define KS   (FCLEN / KSPL)   /* 3136 */
#define KSTEPS (KS / 64)      /* 49 */
#define EPSF 1e-5
#define RB2  512              /* reduce_bn2 blocks */

typedef __attribute__((ext_vector_type(8))) short bf16x8;
typedef __attribute__((ext_vector_type(4))) float f32x4;
typedef __attribute__((ext_vector_type(4))) unsigned int u32x4;

__device__ inline unsigned short f2bf(float f) {
    union { float f; unsigned u; } x; x.f = f;
    unsigned r = x.u + 0x7fffu + ((x.u >> 16) & 1u);
    return (unsigned short)(r >> 16);
}

__device__ inline void gload16(const void* g, void* l) {
    __builtin_amdgcn_global_load_lds((const __attribute__((address_space(1))) unsigned int*)g,
                                     (__attribute__((address_space(3))) unsigned int*)l, 16, 0, 0);
}

__device__ inline void nt_store16(void* addr, const unsigned short* v) {
    u32x4 w;
    memcpy(&w, v, 16);
    __builtin_nontemporal_store(w, (u32x4*)addr);
}

__device__ inline float block_reduce_256(float v, float* red) {
    #pragma unroll
    for (int m = 1; m < 64; m <<= 1) v += __shfl_xor(v, m);
    int wv = threadIdx.x >> 6;
    if ((threadIdx.x & 63) == 0) red[wv] = v;
    __syncthreads();
    float r = 0.f;
    if (threadIdx.x == 0) r = red[0] + red[1] + red[2] + red[3];
    return r;
}

// ---------------- prep_M: M[i][r] = sum_d W_E[i][d]*fc1_w[r][d] ------------
__global__ __launch_bounds__(256) void prep_M(const float* __restrict__ WE,
                                              const float* __restrict__ f1w,
                                              float* __restrict__ Mout) {
    __shared__ float sA[16][17];
    __shared__ float sB[16][17];
    int tx = threadIdx.x, ty = threadIdx.y;
    int r0 = blockIdx.x * 16, i0 = blockIdx.y * 16;
    float acc = 0.f;
    for (int d0 = 0; d0 < DD; d0 += 16) {
        sA[ty][tx] = WE[(size_t)(i0 + ty) * DD + d0 + tx];
        sB[ty][tx] = f1w[(size_t)(r0 + ty) * DD + d0 + tx];
        __syncthreads();
        #pragma unroll
        for (int dd = 0; dd < 16; ++dd) acc = fmaf(sA[ty][dd], sB[tx][dd], acc);
        __syncthreads();
    }
    Mout[(size_t)(i0 + ty) * RR + r0 + tx] = acc;
}

// ------------- stage-1 gathered GEMM body (device, shared smem) ------------
#define S1_SMEM (64 * 72 * 2 + 96 * 72 * 2 + 64 * 4 + 8 * 4)

template <int BN>
__device__ __forceinline__ void gemm_s1_body(const float* __restrict__ A,
                                             const int* __restrict__ idx,
                                             const float* __restrict__ Bm,
                                             const float* __restrict__ bias,
                                             float* __restrict__ C, int N,
                                             float* __restrict__ bn0part,
                                             int bm, int bn, char* smem) {
    constexpr int BNF = BN / 16;
    constexpr int BCH = 64 * (BN / 4) / 256;   // B float4-chunks per thread
    typedef unsigned short us;
    us (*Al)[72] = (us (*)[72])smem;
    us (*Bl)[72] = (us (*)[72])(smem + 64 * 72 * 2);
    int* ridx = (int*)(smem + (64 + 96) * 72 * 2);
    float* red = (float*)(ridx + 64);
    int tid = threadIdx.x;
    if (tid < 64) ridx[tid] = idx[bm * 64 + tid];
    int lane = tid & 63, wv = tid >> 6;
    int m16 = lane & 15, kb = lane >> 4;
    f32x4 acc[BNF];
    #pragma unroll
    for (int nb = 0; nb < BNF; ++nb) acc[nb] = (f32x4){0.f, 0.f, 0.f, 0.f};
    __syncthreads();

    float4 av[4];
    float4 bv[BCH];
    auto LOADR = [&](int k0) {
        #pragma unroll
        for (int r = 0; r < 4; ++r) {
            int c = tid + 256 * r;
            int row = c >> 4, kq = c & 15;
            int gk = k0 + kq * 4;
            av[r] = (float4){0.f, 0.f, 0.f, 0.f};
            if (gk < DD) av[r] = *(const float4*)(A + (size_t)ridx[row] * DD + gk);
        }
        #pragma unroll
        for (int r = 0; r < BCH; ++r) {
            int c = tid + 256 * r;
            int kk2 = c / (BN / 4), nq = c % (BN / 4);
            int gk = k0 + kk2;
            bv[r] = (float4){0.f, 0.f, 0.f, 0.f};
            if (gk < DD) bv[r] = *(const float4*)(Bm + (size_t)gk * N + bn * BN + nq * 4);
        }
    };
    auto WRITELDS = [&]() {
        #pragma unroll
        for (int r = 0; r < 4; ++r) {
            int c = tid + 256 * r;
            int row = c >> 4, kq = c & 15;
            ushort4 p;
            p.x = f2bf(av[r].x); p.y = f2bf(av[r].y); p.z = f2bf(av[r].z); p.w = f2bf(av[r].w);
            *(ushort4*)&Al[row][kq * 4] = p;
        }
        #pragma unroll
        for (int r = 0; r < BCH; ++r) {
            int c = tid + 256 * r;
            int kk2 = c / (BN / 4), nq = c % (BN / 4);
            Bl[nq * 4 + 0][kk2] = f2bf(bv[r].x);
            Bl[nq * 4 + 1][kk2] = f2bf(bv[r].y);
            Bl[nq * 4 + 2][kk2] = f2bf(bv[r].z);
            Bl[nq * 4 + 3][kk2] = f2bf(bv[r].w);
        }
    };

    LOADR(0);
    for (int kt = 0; kt < 7; ++kt) {
        WRITELDS();
        __syncthreads();
        if (kt + 1 < 7) LOADR((kt + 1) * 64);   // latency hides under MFMA
        #pragma unroll
        for (int ks = 0; ks < 2; ++ks) {
            bf16x8 a = *(const bf16x8*)&Al[wv * 16 + m16][ks * 32 + kb * 8];
            #pragma unroll
            for (int nb = 0; nb < BNF; ++nb) {
                bf16x8 b = *(const bf16x8*)&Bl[nb * 16 + m16][ks * 32 + kb * 8];
                acc[nb] = __builtin_amdgcn_mfma_f32_16x16x32_bf16(a, b, acc[nb], 0, 0, 0);
            }
        }
        __syncthreads();
    }
    float s1 = 0.f, s2 = 0.f;
    #pragma unroll
    for (int nb = 0; nb < BNF; ++nb)
        #pragma unroll
        for (int rr = 0; rr < 4; ++rr) {
            int gr = bm * 64 + wv * 16 + kb * 4 + rr;
            int gc = bn * BN + nb * 16 + m16;
            float v = acc[nb][rr];
            if (bias) v += bias[gc];
            C[(size_t)gr * N + gc] = v;
            s1 += v; s2 = fmaf(v, v, s2);
        }
    if (bn0part) {
        float t1 = block_reduce_256(s1, red);
        __syncthreads();
        float t2 = block_reduce_256(s2, red);
        if (tid == 0) {
            int pid = bm * 5 + bn;
            bn0part[pid * 2] = t1; bn0part[pid * 2 + 1] = t2;
        }
    }
}

// Merged stage-1: blocks [0,640) do head GEMM (BN=80, bn0 stats); blocks
// [640,1024) do k GEMM (BN=96, +fc1_b). Fills the machine (~4 blocks/CU).
__global__ __launch_bounds__(256) void gemm_s1_both(const float* __restrict__ UE,
                                                    const int* __restrict__ ht,
                                                    const float* __restrict__ WE,
                                                    const float* __restrict__ Mbuf,
                                                    const float* __restrict__ fc1_b,
                                                    float* __restrict__ head,
                                                    float* __restrict__ kbuf,
                                                    float* __restrict__ bn0part) {
    __shared__ char smem[S1_SMEM];
    int bid = blockIdx.x;
    if (bid < 640) {
        gemm_s1_body<80>(UE, ht, WE, nullptr, head, DD, bn0part, bid / 5, bid % 5, smem);
    } else {
        int b2 = bid - 640;
        gemm_s1_body<96>(UE, ht + BB, Mbuf, fc1_b, kbuf, RR, nullptr, b2 / 3, b2 % 3, smem);
    }
}

// ------ per-sample conv: bn0 finalize fused, 8-wide j, 16B nt stores -------
__global__ __launch_bounds__(256) void conv_k(const float* __restrict__ head,
                                              const float* __restrict__ kbuf,
                                              const float* __restrict__ bn0p,
                                              const float* __restrict__ g0,
                                              const float* __restrict__ b0g,
                                              unsigned short* __restrict__ convb,
                                              float* __restrict__ chpartT) {
    __shared__ float xs[DD];
    __shared__ float ks[RR];
    __shared__ float red[8];
    __shared__ float ab[2];
    int b = blockIdx.x, tid = threadIdx.x;
    for (int i = tid; i < DD; i += 256) xs[i] = head[(size_t)b * DD + i];
    for (int i = tid; i < RR; i += 256) ks[i] = kbuf[(size_t)b * RR + i];
    // bn0 finalize (redundant per block, tiny)
    float p1 = 0.f, p2 = 0.f;
    for (int i = tid; i < 640; i += 256) { p1 += bn0p[i * 2]; p2 += bn0p[i * 2 + 1]; }
    float t1 = block_reduce_256(p1, red);
    __syncthreads();
    float t2 = block_reduce_256(p2, red);
    if (tid == 0) {
        double n = (double)BB * DD;
        double mean = (double)t1 / n;
        double var = (double)t2 / n - mean * mean;
        float a0 = (float)((double)g0[0] / sqrt(var + EPSF));
        ab[0] = a0; ab[1] = (float)((double)b0g[0] - mean * a0);
    }
    __syncthreads();
    float a0 = ab[0], b0 = ab[1];
    int lane = tid & 63, wv = tid >> 6;
    unsigned short* orow = convb + (size_t)b * FCLEN;
    float kk[8][FWW];
    #pragma unroll
    for (int oi = 0; oi < 8; ++oi)
        #pragma unroll
        for (int w2 = 0; w2 < FWW; ++w2) kk[oi][w2] = ks[(wv * 8 + oi) * FWW + w2];
    float s1[8], s2[8];
    #pragma unroll
    for (int oi = 0; oi < 8; ++oi) { s1[oi] = 0.f; s2[oi] = 0.f; }
    int j0 = lane * 8;                        // lanes 0..48 active (392/8=49)
    bool act = j0 < JJ;
    float x[16];
    if (act) {
        const float4* x4 = (const float4*)xs;
        float4 v0 = x4[(j0 >> 2) + 0], v1 = x4[(j0 >> 2) + 1];
        float4 v2 = x4[(j0 >> 2) + 2], v3 = x4[(j0 >> 2) + 3];
        float xr[16] = {v0.x, v0.y, v0.z, v0.w, v1.x, v1.y, v1.z, v1.w,
                        v2.x, v2.y, v2.z, v2.w, v3.x, v3.y, v3.z, v3.w};
        #pragma unroll
        for (int q = 0; q < 16; ++q) x[q] = fmaf(xr[q], a0, b0);
    }
    #pragma unroll
    for (int oi = 0; oi < 8; ++oi) {
        if (act) {
            unsigned short p[8];
            #pragma unroll
            for (int q = 0; q < 8; ++q) {
                float a = 0.f;
                #pragma unroll
                for (int w2 = 0; w2 < FWW; ++w2) a = fmaf(x[q + w2], kk[oi][w2], a);
                p[q] = f2bf(a);
                s1[oi] += a; s2[oi] = fmaf(a, a, s2[oi]);
            }
            nt_store16(orow + (wv * 8 + oi) * JJ + j0, p);
        }
    }
    #pragma unroll
    for (int oi = 0; oi < 8; ++oi) {
        float a = s1[oi], c = s2[oi];
        #pragma unroll
        for (int m = 1; m < 64; m <<= 1) { a += __shfl_xor(a, m); c += __shfl_xor(c, m); }
        if (lane == 0) {
            int o = wv * 8 + oi;
            chpartT[(size_t)o * BB + b] = a;
            chpartT[(size_t)(OCC + o) * BB + b] = c;
        }
    }
}

__global__ __launch_bounds__(256) void bn1_fin(const float* __restrict__ chpartT,
                                               const float* __restrict__ g1,
                                               const float* __restrict__ b1,
                                               float* __restrict__ alphabeta) {
    __shared__ float red[8];
    int o = blockIdx.x, tid = threadIdx.x;
    float s1 = 0.f, s2 = 0.f;
    for (int t = tid; t < BB; t += 256) {
        s1 += chpartT[(size_t)o * BB + t];
        s2 += chpartT[(size_t)(OCC + o) * BB + t];
    }
    float t1 = block_reduce_256(s1, red);
    __syncthreads();
    float t2 = block_reduce_256(s2, red);
    if (tid == 0) {
        double n = (double)BB * JJ;
        double mean = (double)t1 / n;
        double var = (double)t2 / n - mean * mean;
        float al = (float)((double)g1[o] / sqrt(var + EPSF));
        float be = (float)((double)b1[o] - mean * al);
        alphabeta[o] = al; alphabeta[OCC + o] = be;
    }
}

// ------- fold bn1 into fc_w: Bprep = bf16(fc_w*alpha); bias2 (f4 vec) ------
__global__ __launch_bounds__(256) void prep_fcw(const float* __restrict__ fc_w,
                                                const float* __restrict__ fc_b,
                                                const float* __restrict__ alphabeta,
                                                unsigned short* __restrict__ Bp,
                                                float* __restrict__ bias2) {
    __shared__ float al[OCC], be[OCC];
    __shared__ float red[8];
    int d = blockIdx.x, tid = threadIdx.x;
    if (tid < OCC) { al[tid] = alphabeta[tid]; be[tid] = alphabeta[OCC + tid]; }
    __syncthreads();
    const float4* row4 = (const float4*)(fc_w + (size_t)d * FCLEN);
    ushort4* orow4 = (ushort4*)(Bp + (size_t)d * FCLEN);
    float bacc = 0.f;
    for (int c = tid; c < FCLEN / 4; c += 256) {     // 3136 float4; 392%4==0
        float4 v = row4[c];
        int o = c / (JJ / 4);                        // c/98
        float a = al[o], bb = be[o];
        ushort4 p;
        p.x = f2bf(v.x * a); p.y = f2bf(v.y * a);
        p.z = f2bf(v.z * a); p.w = f2bf(v.w * a);
        orow4[c] = p;
        bacc = fmaf(v.x + v.y + v.z + v.w, bb, bacc);
    }
    float t = block_reduce_256(bacc, red);
    if (tid == 0) bias2[d] = fc_b[d] + t;
}

// -------- big FC GEMM, split-K=4, BM=256 BN=80, 4 waves x (64x80) ----------
// R8 structure (best measured, ~130us, 0 conflicts): single-buffer LDS 42KB
// -> 3 blocks/CU, global_load_lds + both-sides XOR swizzle, simple barrier
// loop, bijective XCD swizzle over the flat 640-block grid (640 = 8 x 80).
// NOTE: five pipeline variants (R3/R6/R7/R9/R12 - dbuf, counted-vmcnt,
// depth-2 triple-buffer) all regressed vs this plain loop: pipeline depth
// here trades occupancy (the actual latency-hider at 3 blk/CU) for nothing.
__global__ __launch_bounds__(256, 3) void fc_gemm_sk(const unsigned short* __restrict__ A,
                                                     const unsigned short* __restrict__ Bp,
                                                     float* __restrict__ P) {
    __shared__ __align__(16) unsigned short Al[256 * 64];   // 32 KiB, 32 chunks
    __shared__ __align__(16) unsigned short Bl[80 * 64];    // 10 KiB, 10 chunks
    int tid = threadIdx.x;
    // bijective XCD swizzle: nwg = 640 = 8 x 80; consecutive swizzled ids on
    // one XCD share the same (bm,bz) A-panel (bn varies fastest) -> L2 reuse.
    int orig = blockIdx.x;
    int wgid = (orig & 7) * 80 + (orig >> 3);
    int bn = wgid % 5;
    int rest = wgid / 5;            // 0..127
    int bm = rest & 31;
    int bz = rest >> 5;             // 0..3
    int lane = tid & 63, wv = tid >> 6;
    int m16 = lane & 15, kb = lane >> 4;
    int srow = lane >> 3, scol = lane & 7;    // staging lane -> (row-in-chunk, 16B slot)
    int sw = m16 & 7;                          // read-side XOR term (row & 7)
    f32x4 acc[4][5];
    #pragma unroll
    for (int mi = 0; mi < 4; ++mi)
        #pragma unroll
        for (int nb = 0; nb < 5; ++nb) acc[mi][nb] = (f32x4){0.f, 0.f, 0.f, 0.f};

    // per-lane pre-swizzled global sources (chunk = 1KB = 8 rows x 64 cols)
    const unsigned short* Asrc = A + (size_t)(bm * 256 + srow) * FCLEN
                                   + (size_t)bz * KS + ((scol ^ srow) << 3);
    const unsigned short* Bsrc = Bp + (size_t)(bn * 80 + srow) * FCLEN
                                   + (size_t)bz * KS + ((scol ^ srow) << 3);

    for (int kt = 0; kt < KSTEPS; ++kt) {
        const size_t koff = (size_t)kt * 64;
        // 42 chunks total: 32 A + 10 B, wave wv takes chunks wv+4i
        #pragma unroll
        for (int i = 0; i < 11; ++i) {
            int c = wv + i * 4;
            if (c < 32) {
                gload16(Asrc + (size_t)c * 8 * FCLEN + koff, Al + c * 512);
            } else if (c < 42) {
                int cb = c - 32;
                gload16(Bsrc + (size_t)cb * 8 * FCLEN + koff, Bl + cb * 512);
            }
        }
        __syncthreads();
        #pragma unroll
        for (int ks2 = 0; ks2 < 2; ++ks2) {
            int ch = (((ks2 * 4 + kb) ^ sw) << 3);
            bf16x8 a[4];
            #pragma unroll
            for (int mi = 0; mi < 4; ++mi)
                a[mi] = *(const bf16x8*)(Al + (wv * 64 + mi * 16 + m16) * 64 + ch);
            #pragma unroll
            for (int nb = 0; nb < 5; ++nb) {
                bf16x8 b = *(const bf16x8*)(Bl + (nb * 16 + m16) * 64 + ch);
                #pragma unroll
                for (int mi = 0; mi < 4; ++mi)
                    acc[mi][nb] = __builtin_amdgcn_mfma_f32_16x16x32_bf16(a[mi], b, acc[mi][nb], 0, 0, 0);
            }
        }
        __syncthreads();
    }

    float* Po = P + (size_t)bz * BB * DD;
    #pragma unroll
    for (int mi = 0; mi < 4; ++mi)
        #pragma unroll
        for (int nb = 0; nb < 5; ++nb)
            #pragma unroll
            for (int rr = 0; rr < 4; ++rr) {
                int gr = bm * 256 + wv * 64 + mi * 16 + kb * 4 + rr;
                int gc = bn * 80 + nb * 16 + m16;
                Po[(size_t)gr * DD + gc] = acc[mi][nb][rr];
            }
}

// ------ reduce split-K partials + bias, emit bn2 per-column partials -------
__global__ __launch_bounds__(256) void reduce_bn2(const float* __restrict__ P,
                                                  const float* __restrict__ bias2,
                                                  float* __restrict__ out,
                                                  float* __restrict__ part) {
    int blk = blockIdx.x, tid = threadIdx.x;   // RB2 blocks x 16 rows
    int r0 = blk * 16;
    const size_t S = (size_t)BB * DD;
    bool hasb = tid < DD - 256;
    float bia = bias2[tid];
    float bib = hasb ? bias2[256 + tid] : 0.f;
    float s1a = 0.f, s2a = 0.f, s1b = 0.f, s2b = 0.f;
    for (int r = 0; r < 16; ++r) {
        size_t base = (size_t)(r0 + r) * DD;
        float v = P[base + tid] + P[S + base + tid] + P[2 * S + base + tid] + P[3 * S + base + tid] + bia;
        out[base + tid] = v;
        s1a += v; s2a = fmaf(v, v, s2a);
        if (hasb) {
            size_t b2i = base + 256 + tid;
            float u = P[b2i] + P[S + b2i] + P[2 * S + b2i] + P[3 * S + b2i] + bib;
            out[b2i] = u;
            s1b += u; s2b = fmaf(u, u, s2b);
        }
    }
    float* p = part + (size_t)blk * (DD * 2);
    p[tid * 2] = s1a; p[tid * 2 + 1] = s2a;
    if (hasb) { p[(256 + tid) * 2] = s1b; p[(256 + tid) * 2 + 1] = s2b; }
}

__global__ __launch_bounds__(128) void bn2_fin(const float* __restrict__ part,
                                               const float* __restrict__ g2,
                                               const float* __restrict__ b2,
                                               float* __restrict__ sc,
                                               float* __restrict__ sh) {
    __shared__ float red[4];
    int col = blockIdx.x, tid = threadIdx.x;
    float s1 = 0.f, s2 = 0.f;
    for (int t = tid; t < RB2; t += 128) {
        s1 += part[(size_t)t * (DD * 2) + col * 2];
        s2 += part[(size_t)t * (DD * 2) + col * 2 + 1];
    }
    #pragma unroll
    for (int m = 1; m < 64; m <<= 1) { s1 += __shfl_xor(s1, m); s2 += __shfl_xor(s2, m); }
    int wv = tid >> 6;
    if ((tid & 63) == 0) { red[wv] = s1; red[2 + wv] = s2; }
    __syncthreads();
    if (tid == 0) {
        double t1 = (double)red[0] + red[1];
        double t2 = (double)red[2] + red[3];
        double mean = t1 / (double)BB;
        double var = t2 / (double)BB - mean * mean;
        float s = (float)((double)g2[col] / sqrt(var + EPSF));
        sc[col] = s;
        sh[col] = (float)((double)b2[col] - mean * s);
    }
}

// ---------------- final scale+shift+relu, float4-vectorized ----------------
__global__ __launch_bounds__(256) void final_k(float* __restrict__ out,
                                               const float* __restrict__ sc,
                                               const float* __restrict__ sh) {
    __shared__ float lsc[DD], lsh[DD];
    int tid = threadIdx.x;
    for (int c = tid; c < DD; c += 256) { lsc[c] = sc[c]; lsh[c] = sh[c]; }
    __syncthreads();
    int r0 = blockIdx.x * 8;                       // 1024 blocks x 8 rows
    float4* out4 = (float4*)(out + (size_t)r0 * DD);
    for (int c = tid; c < 8 * DD / 4; c += 256) {  // 800 float4
        int row = c / (DD / 4), c4 = c % (DD / 4);
        float4 v = out4[(size_t)row * (DD / 4) + c4];
        int cb = c4 * 4;
        v.x = fmaf(v.x, lsc[cb + 0], lsh[cb + 0]); v.x = v.x > 0.f ? v.x : 0.f;
        v.y = fmaf(v.y, lsc[cb + 1], lsh[cb + 1]); v.y = v.y > 0.f ? v.y : 0.f;
        v.z = fmaf(v.z, lsc[cb + 2], lsh[cb + 2]); v.z = v.z > 0.f ? v.z : 0.f;
        v.w = fmaf(v.w, lsc[cb + 3], lsh[cb + 3]); v.w = v.w > 0.f ? v.w : 0.f;
        out4[(size_t)row * (DD / 4) + c4] = v;
    }
}

// ---------------------------------------------------------------------------
extern "C" void kernel_launch(void* const* d_in, const int* in_sizes, int n_in,
                              void* d_out, int out_size, void* d_ws, size_t ws_size,
                              hipStream_t stream) {
    const int* ht      = (const int*)d_in[0];
    const float* UE    = (const float*)d_in[1];
    const float* W_E   = (const float*)d_in[2];
    const float* fc1_w = (const float*)d_in[3];
    const float* fc1_b = (const float*)d_in[4];
    const float* fc_w  = (const float*)d_in[5];
    const float* fc_b  = (const float*)d_in[6];
    const float* bn0_g = (const float*)d_in[7];
    const float* bn0_b = (const float*)d_in[8];
    const float* bn1_g = (const float*)d_in[9];
    const float* bn1_b = (const float*)d_in[10];
    const float* bn2_g = (const float*)d_in[11];
    const float* bn2_b = (const float*)d_in[12];
    float* out = (float*)d_out;

    char* w = (char*)d_ws;
    unsigned short* convb = (unsigned short*)w; w += (size_t)BB * FCLEN * 2;      // 205.5 MB
    unsigned short* Bprep = (unsigned short*)w; w += (size_t)DD * FCLEN * 2;      // 10 MB
    float* chpartT = (float*)w; w += (size_t)2 * OCC * BB * 4;                    // 2.1 MB
    float* bn0p = (float*)w;  w += 640 * 2 * 4;
    float* alphabeta = (float*)w; w += 64 * 4;
    float* bias2 = (float*)w; w += DD * 4;
    float* bn2p = (float*)w;  w += (size_t)RB2 * DD * 2 * 4;
    float* bn2sc = (float*)w; w += DD * 4;
    float* bn2sh = (float*)w; w += DD * 4;
    // split-K partial region (52.4 MB), aliased over head/kbuf/Mbuf (dead by
    // the time fc_gemm_sk runs):
    float* P = (float*)w;     w += (size_t)KSPL * BB * DD * 4;
    float* head = P;                      // 13.1 MB, consumed by conv_k
    float* kbuf = head + (size_t)BB * DD; // 9.4 MB, consumed by conv_k
    float* Mbuf = kbuf + (size_t)BB * RR; // 0.46 MB, consumed by gemm_s1_both
    (void)ws_size; (void)in_sizes; (void)n_in; (void)out_size;

    prep_M<<<dim3(RR / 16, DD / 16), dim3(16, 16), 0, stream>>>(W_E, fc1_w, Mbuf);
    gemm_s1_both<<<1024, 256, 0, stream>>>(UE, ht, W_E, Mbuf, fc1_b, head, kbuf, bn0p);
    conv_k<<<BB, 256, 0, stream>>>(head, kbuf, bn0p, bn0_g, bn0_b, convb, chpartT);
    bn1_fin<<<OCC, 256, 0, stream>>>(chpartT, bn1_g, bn1_b, alphabeta);
    prep_fcw<<<DD, 256, 0, stream>>>(fc_w, fc_b, alphabeta, Bprep, bias2);
    fc_gemm_sk<<<dim3(32 * 5 * KSPL), 256, 0, stream>>>(convb, Bprep, P);
    reduce_bn2<<<RB2, 256, 0, stream>>>(P, bias2, out, bn2p);
    bn2_fin<<<DD, 128, 0, stream>>>(bn2p, bn2_g, bn2_b, bn2sc, bn2sh);
    final_k<<<BB / 8, 256, 0, stream>>>(out, bn2sc, bn2sh);
}